// Round 6
// baseline (221.447 us; speedup 1.0000x reference)
//
#include <hip/hip_runtime.h>
#include <hip/hip_bf16.h>

typedef short bs8 __attribute__((ext_vector_type(8)));
typedef short bs4 __attribute__((ext_vector_type(4)));
typedef float f32x4 __attribute__((ext_vector_type(4)));

#define B_ 4
#define L_ 2048
#define H_ 16
#define E_ 64
#define QT_ 128   // q rows per block (4 waves x 32 rows, 2 strips of 16)
#define KT_ 64    // keys per tile
#define KSTR 72   // LDS stride (shorts): 144B rows, b128 frag reads at bank floor
#define NEG_INF (-1e30f)
#define SCALE_LOG2E (0.125f * 1.44269504088896340736f)

__device__ __forceinline__ short bf16of(float x) {
  __hip_bfloat16 h = __float2bfloat16(x);
  return *reinterpret_cast<short*>(&h);
}
__device__ __forceinline__ unsigned pk2(float a, float b) {
  return (unsigned)(unsigned short)bf16of(a) |
         ((unsigned)(unsigned short)bf16of(b) << 16);
}

// ---------- Fused prepass (unchanged from R5, verified correct) ----------
__global__ __launch_bounds__(256) void prep(const float* __restrict__ K,
                                            const float* __restrict__ V,
                                            short* __restrict__ Kb,
                                            short* __restrict__ Vt) {
  __shared__ unsigned int lt[64 * 35];   // [e][s_pair] packed 2x bf16
  const int tid = threadIdx.x;
  if (blockIdx.x < 2048) {
    size_t base = (size_t)blockIdx.x * 256 + tid;   // 16B-chunk index of Kb
#pragma unroll
    for (int i = 0; i < 2; ++i) {
      size_t u = base + (size_t)i * 524288;         // < 2^20
      int e8 = u & 7;
      int h  = (u >> 3) & 15;
      int s  = (u >> 7) & 2047;
      int b  = (int)(u >> 18);                      // 0..3
      float4 f0 = *(const float4*)(K + u * 8);
      float4 f1 = *(const float4*)(K + u * 8 + 4);
      bs8 o;
      o[0] = bf16of(f0.x); o[1] = bf16of(f0.y); o[2] = bf16of(f0.z); o[3] = bf16of(f0.w);
      o[4] = bf16of(f1.x); o[5] = bf16of(f1.y); o[6] = bf16of(f1.z); o[7] = bf16of(f1.w);
      *(bs8*)(Kb + (((size_t)(b * 16 + h) * L_ + s) * E_ + e8 * 8)) = o;
    }
  } else {
    int vb = blockIdx.x - 2048;   // 0..2047
    int st = vb & 31, bh = vb >> 5;
    int b = bh >> 4, h = bh & 15;
    int s0 = st * 64;
#pragma unroll
    for (int i = 0; i < 2; ++i) {
      int idx = i * 256 + tid;       // 0..511
      int sp = idx >> 4;             // s-pair 0..31
      int e4 = idx & 15;
      const float* p0 = V + (((size_t)b * L_ + s0 + 2 * sp) * H_ + h) * E_ + e4 * 4;
      float4 v0 = *(const float4*)p0;
      float4 v1 = *(const float4*)(p0 + H_ * E_);
      lt[(e4 * 4 + 0) * 35 + sp] = pk2(v0.x, v1.x);
      lt[(e4 * 4 + 1) * 35 + sp] = pk2(v0.y, v1.y);
      lt[(e4 * 4 + 2) * 35 + sp] = pk2(v0.z, v1.z);
      lt[(e4 * 4 + 3) * 35 + sp] = pk2(v0.w, v1.w);
    }
    __syncthreads();
#pragma unroll
    for (int i = 0; i < 2; ++i) {
      int idx = i * 256 + tid;
      int e  = idx >> 3;             // 0..63
      int s8 = idx & 7;              // 8-key group
      uint4 o;
      o.x = lt[e * 35 + s8 * 4 + 0];
      o.y = lt[e * 35 + s8 * 4 + 1];
      o.z = lt[e * 35 + s8 * 4 + 2];
      o.w = lt[e * 35 + s8 * 4 + 3];
      *(uint4*)(Vt + ((size_t)bh * E_ + e) * L_ + s0 + 8 * s8) = o;
    }
  }
}

// ---------- Main flash-attention kernel ----------
// Grid (16, 64), big-first (qt = 15-bx) for LPT balance; 3 blocks/CU.
// S^T = K·Q^T via 16x16x32 (swapped operands). The C-layout result
// (key=quad*4+r, q=l16) IS the A-operand layout of mfma_f32_16x16x16_bf16
// (A[m=l16][k=quad*4+j]) -> PV directly from registers. No ldsP, no fence.
// ldsV stores keys bit-swizzled (c' = q4*16 + mt*4 + j) so one b128 read
// yields two mt B-frags (B[k=quad*4+j][n=l16]).
__global__ __launch_bounds__(256, 3) void flash_fwd(const float* __restrict__ Q,
                                                    const short* __restrict__ Kb,
                                                    const short* __restrict__ Vt,
                                                    float* __restrict__ O) {
  const int qt = 15 - blockIdx.x;   // big blocks dispatch first
  const int bh = blockIdx.y;        // 0..63
  const int b = bh >> 4, h = bh & 15;
  const int tid = threadIdx.x;
  const int w = tid >> 6;
  const int lane = tid & 63;
  const int quad = lane >> 4;
  const int l16 = lane & 15;

  __shared__ short ldsK[KT_ * KSTR];    // [key][dim]
  __shared__ short ldsV[E_ * KSTR];     // [dim][key-swizzled]

  const short* KbBase = Kb + (size_t)bh * L_ * E_;
  const short* VtBase = Vt + (size_t)bh * E_ * L_;

  // staging coords (per thread): rows sr, sr+32; cols sc..sc+7
  const int sr = tid >> 3;          // 0..31
  const int sc = (tid & 7) * 8;
  // V staging swizzle: global 8-key chunk kc -> two b64 at c0, c0+16
  const int kc = tid & 7;
  const int vc0 = 32 * (kc & 1) + 4 * (kc >> 1);

  const int q0 = qt * QT_;
  const int nkt = 2 * qt + 2;

  // ---- Q B-frags: 2 strips of 16 rows (pre-scaled, exp2 domain) ----
  bs8 aQ[2][2];
#pragma unroll
  for (int st = 0; st < 2; ++st) {
    const int q = q0 + w * 32 + st * 16 + l16;
    const float* qp = Q + (((size_t)b * L_ + q) * H_ + h) * E_ + quad * 8;
#pragma unroll
    for (int c = 0; c < 2; ++c) {
      float4 f0 = *(const float4*)(qp + c * 32);
      float4 f1 = *(const float4*)(qp + c * 32 + 4);
      bs8 a;
      a[0] = bf16of(f0.x * SCALE_LOG2E); a[1] = bf16of(f0.y * SCALE_LOG2E);
      a[2] = bf16of(f0.z * SCALE_LOG2E); a[3] = bf16of(f0.w * SCALE_LOG2E);
      a[4] = bf16of(f1.x * SCALE_LOG2E); a[5] = bf16of(f1.y * SCALE_LOG2E);
      a[6] = bf16of(f1.z * SCALE_LOG2E); a[7] = bf16of(f1.w * SCALE_LOG2E);
      aQ[st][c] = a;
    }
  }

  f32x4 accO[2][4];
  float accLp[2];
#pragma unroll
  for (int st = 0; st < 2; ++st) {
    accLp[st] = 0.f;
#pragma unroll
    for (int nt = 0; nt < 4; ++nt) accO[st][nt] = (f32x4){0.f, 0.f, 0.f, 0.f};
  }

  // ---- prefetch tile 0 into registers ----
  bs8 pfK[2], pfV[2];
#pragma unroll
  for (int i = 0; i < 2; ++i) {
    pfK[i] = *(const bs8*)(KbBase + (size_t)(sr + 32 * i) * E_ + sc);
    pfV[i] = *(const bs8*)(VtBase + (size_t)(sr + 32 * i) * L_ + sc);
  }

  for (int kt = 0; kt < nkt; ++kt) {
    const int k0 = kt * KT_;
    __syncthreads();   // previous tile's LDS reads complete

    // ---- commit prefetched tile to LDS ----
#pragma unroll
    for (int i = 0; i < 2; ++i) {
      *(bs8*)&ldsK[(sr + 32 * i) * KSTR + sc] = pfK[i];
      // V: split bs8 into two b64 at swizzled columns
      bs4 lo = __builtin_shufflevector(pfV[i], pfV[i], 0, 1, 2, 3);
      bs4 hi = __builtin_shufflevector(pfV[i], pfV[i], 4, 5, 6, 7);
      *(bs4*)&ldsV[(sr + 32 * i) * KSTR + vc0] = lo;
      *(bs4*)&ldsV[(sr + 32 * i) * KSTR + vc0 + 16] = hi;
    }
    // ---- prefetch next tile ----
    if (kt + 1 < nkt) {
      const int kn = k0 + KT_;
#pragma unroll
      for (int i = 0; i < 2; ++i) {
        pfK[i] = *(const bs8*)(KbBase + (size_t)(kn + sr + 32 * i) * E_ + sc);
        pfV[i] = *(const bs8*)(VtBase + (size_t)(sr + 32 * i) * L_ + kn + sc);
      }
    }
    __syncthreads();

    bool act0 = (k0 <= q0 + w * 32 + 15);
    bool act1 = (k0 <= q0 + w * 32 + 31);

    if (act1) {
      // ---- K A-frags (shared across both strips) ----
      bs8 aK0[4], aK1[4];
#pragma unroll
      for (int mt = 0; mt < 4; ++mt) {
        aK0[mt] = *(const bs8*)&ldsK[(mt * 16 + l16) * KSTR + quad * 8];
        aK1[mt] = *(const bs8*)&ldsK[(mt * 16 + l16) * KSTR + 32 + quad * 8];
      }

      // ---- per strip: S^T -> mask -> exp2 -> packed P A-frags (registers) ----
      bs4 aPf[2][4];   // [strip][mt]: 4 bf16 = keys quad*4+j, query l16
#pragma unroll
      for (int st = 0; st < 2; ++st) {
        bool act = st ? act1 : act0;
        if (act) {
          const int qg = q0 + w * 32 + st * 16 + l16;   // this lane's query
          const bool diag = (k0 + KT_ - 1 > q0 + w * 32 + st * 16);
          float rs = 0.f;
#pragma unroll
          for (int mt = 0; mt < 4; ++mt) {
            f32x4 acc = (f32x4){0.f, 0.f, 0.f, 0.f};
            acc = __builtin_amdgcn_mfma_f32_16x16x32_bf16(aK0[mt], aQ[st][0], acc, 0, 0, 0);
            acc = __builtin_amdgcn_mfma_f32_16x16x32_bf16(aK1[mt], aQ[st][1], acc, 0, 0, 0);
            if (diag) {
              const int kb = k0 + mt * 16 + quad * 4;
#pragma unroll
              for (int r = 0; r < 4; ++r)
                if (kb + r > qg) acc[r] = NEG_INF;
            }
            float p0 = __builtin_amdgcn_exp2f(acc[0]);
            float p1 = __builtin_amdgcn_exp2f(acc[1]);
            float p2 = __builtin_amdgcn_exp2f(acc[2]);
            float p3 = __builtin_amdgcn_exp2f(acc[3]);
            rs += (p0 + p1) + (p2 + p3);
            union { unsigned u[2]; bs4 v; } cv;
            cv.u[0] = pk2(p0, p1);
            cv.u[1] = pk2(p2, p3);
            aPf[st][mt] = cv.v;
          }
          accLp[st] += rs;
        }
      }

      // ---- O += P V via 16x16x16 MFMA, B-frags from swizzled ldsV ----
#pragma unroll
      for (int nt = 0; nt < 4; ++nt) {
#pragma unroll
        for (int hf = 0; hf < 2; ++hf) {
          bs8 bV = *(const bs8*)&ldsV[(nt * 16 + l16) * KSTR + quad * 16 + hf * 8];
          bs4 blo = __builtin_shufflevector(bV, bV, 0, 1, 2, 3);  // mt = 2hf
          bs4 bhi = __builtin_shufflevector(bV, bV, 4, 5, 6, 7);  // mt = 2hf+1
#pragma unroll
          for (int st = 0; st < 2; ++st) {
            if (st ? act1 : act0) {
              accO[st][nt] = __builtin_amdgcn_mfma_f32_16x16x16bf16_1k(
                  aPf[st][2 * hf], blo, accO[st][nt], 0, 0, 0);
              accO[st][nt] = __builtin_amdgcn_mfma_f32_16x16x16bf16_1k(
                  aPf[st][2 * hf + 1], bhi, accO[st][nt], 0, 0, 0);
            }
          }
        }
      }
    }
  }

  // ---- epilogue: reduce l across quads, broadcast to C-rows, O / l ----
#pragma unroll
  for (int st = 0; st < 2; ++st) {
    float lf = accLp[st];
    lf += __shfl_xor(lf, 16, 64);
    lf += __shfl_xor(lf, 32, 64);   // all lanes now hold full l(q = base + l16)
    float inv[4];
#pragma unroll
    for (int r = 0; r < 4; ++r)
      inv[r] = 1.f / __shfl(lf, quad * 4 + r, 64);   // l of this lane's C-row
#pragma unroll
    for (int nt = 0; nt < 4; ++nt) {
      const int q = q0 + w * 32 + st * 16 + quad * 4;   // + r
      const int d = nt * 16 + l16;
      float* op = O + (((size_t)b * L_ + q) * H_ + h) * E_ + d;
#pragma unroll
      for (int r = 0; r < 4; ++r)
        op[(size_t)r * H_ * E_] = accO[st][nt][r] * inv[r];
    }
  }
}

extern "C" void kernel_launch(void* const* d_in, const int* in_sizes, int n_in,
                              void* d_out, int out_size, void* d_ws, size_t ws_size,
                              hipStream_t stream) {
  (void)in_sizes; (void)n_in; (void)out_size; (void)ws_size;
  const float* Q = (const float*)d_in[0];
  const float* K = (const float*)d_in[1];
  const float* V = (const float*)d_in[2];
  float* Out = (float*)d_out;
  short* Kb = (short*)d_ws;                              // 16.78 MB
  short* Vt = Kb + (size_t)B_ * H_ * L_ * E_;            // +16.78 MB

  prep<<<4096, 256, 0, stream>>>(K, V, Kb, Vt);
  flash_fwd<<<dim3(16, 64), 256, 0, stream>>>(Q, Kb, Vt, Out);
}